// Round 13
// baseline (131.475 us; speedup 1.0000x reference)
//
#include <hip/hip_runtime.h>
#include <hip/hip_bf16.h>
#include <cstdint>

#define KDIM 32
#define RMAX 8
#define CAPL 1280   // LDS slots per block (chunk<=1152 + 128 pad)
#define GMAX 128

typedef _Float16 half2v __attribute__((ext_vector_type(2)));
typedef _Float16 half4v __attribute__((ext_vector_type(4)));
typedef float    f32x4  __attribute__((ext_vector_type(4)));

#if __has_builtin(__builtin_amdgcn_mfma_f32_16x16x16f16)
#define USE_MFMA 1
#else
#define USE_MFMA 0
#endif

__device__ __forceinline__ float sigmoidf_(float x) {
    return 1.0f / (1.0f + expf(-x));
}

__device__ __forceinline__ float gate_weight_(float logit, float log_alpha) {
    // hard-concrete eval gate: pre = clip(la/temp, -2, 2); z = sig(pre)*1.2-0.1; clip[0,1]
    float pre = log_alpha * 1.5f;                 // / (2/3)
    pre = fminf(fmaxf(pre, -2.0f), 2.0f);
    float z = sigmoidf_(pre) * 1.2f - 0.1f;
    z = fminf(fmaxf(z, 0.0f), 1.0f);
    return sigmoidf_(logit) * z;
}

// ---- kernel 1: W->f16 + A->f16 conversion (validated prep, hist removed) ----
__global__ __launch_bounds__(256) void prep3_kernel(
    const float* __restrict__ logits, const float* __restrict__ la,
    _Float16* __restrict__ Wh, int n,
    const float* __restrict__ A, _Float16* __restrict__ Ah, int nA) {
    int g = blockIdx.x * blockDim.x + threadIdx.x;
    if (g < n) Wh[g] = (_Float16)gate_weight_(logits[g], la[g]);

    int nthreads = gridDim.x * blockDim.x;
    int n4 = nA >> 2;
    for (int i4 = g; i4 < n4; i4 += nthreads) {
        float4 v = ((const float4*)A)[i4];
        half2v h0; h0[0] = (_Float16)v.x; h0[1] = (_Float16)v.y;
        half2v h1; h1[0] = (_Float16)v.z; h1[1] = (_Float16)v.w;
        ((half2v*)Ah)[i4 * 2 + 0] = h0;
        ((half2v*)Ah)[i4 * 2 + 1] = h1;
    }
}

#if USE_MFMA
// ---- kernel 2: fused local-sort + MFMA compute.
// Block sorts its chunk into 8 LDS buckets padded to 16 (storing sn,dn,e),
// then each wave processes 16-edge groups with group-uniform relation.
// MFMA math identical to the round-9/12-validated gather4:
//   A-frag: lane l reg i = M[l%16][(l/16)*4+i]
//   B-frag: lane l reg i = M[(l/16)*4+i][l%16]
//   C:      lane l reg q = M[(l/16)*4+q][l%16]   (== B-frag mapping)
__global__ __launch_bounds__(256) void fused_kernel(
    const _Float16* __restrict__ Ah, const _Float16* __restrict__ Wh,
    const float* __restrict__ bias, const int* __restrict__ ei,
    const int* __restrict__ et, float* __restrict__ out, int E, int chunk) {
    __shared__ int sn_l[CAPL], dn_l[CAPL], e_l[CAPL];
    __shared__ int cnt[RMAX], cur[RMAX], pb[RMAX + 1];
    __shared__ int rg[GMAX];
    __shared__ int ng_s;

    int t = threadIdx.x;
    int b = blockIdx.x;
    int start = b * chunk;
    int end = start + chunk;
    if (end > E) end = E;

    // phase 0: zero counters
    if (t < RMAX) cnt[t] = 0;
    __syncthreads();

    // phase 1: count
    for (int i = start + t; i < end; i += 256) {
        atomicAdd(&cnt[et[i]], 1);
    }
    __syncthreads();

    // phase 2: padded prefix (pad each bucket to multiple of 16)
    if (t == 0) {
        int o = 0;
        pb[0] = 0;
#pragma unroll
        for (int r = 0; r < RMAX; r++) {
            cur[r] = o;
            o += (cnt[r] + 15) & ~15;
            pb[r + 1] = o;
        }
        ng_s = o >> 4;
    }
    __syncthreads();

    // phase 3a: group -> relation map
    int ng = ng_s;
    for (int g = t; g < ng; g += 256) {
        int s16 = g << 4;
        int r = 0;
#pragma unroll
        for (int rr = 1; rr < RMAX; rr++) r += (s16 >= pb[rr]) ? 1 : 0;
        rg[g] = r;
    }
    // phase 3b: pad slots (disjoint from placed slots)
#pragma unroll
    for (int r = 0; r < RMAX; r++) {
        int ps = pb[r] + cnt[r];
        int pe = pb[r + 1];
        for (int i = ps + t; i < pe; i += 256) {
            e_l[i] = -1; sn_l[i] = 0; dn_l[i] = 0;
        }
    }
    // phase 3c: place (coalesced global reads, LDS-atomic positions)
    for (int i = start + t; i < end; i += 256) {
        int r = et[i];
        int sn = ei[i];
        int dn = ei[E + i];
        int pos = atomicAdd(&cur[r], 1);
        sn_l[pos] = sn; dn_l[pos] = dn; e_l[pos] = i;
    }
    __syncthreads();

    // phase 4: compute, one 16-edge group per wave-iteration
    int wid = t >> 6;
    int lane = t & 63;
    int lm = lane & 15;
    int lg = lane >> 4;
    int kq = lg * 4;
    f32x4 zeroF = {0.0f, 0.0f, 0.0f, 0.0f};
    bool diag_lane = (lg == (lm >> 2));

    for (int g = wid; g < ng; g += 4) {
        int r = rg[g];                       // LDS broadcast, group-uniform
        r = __builtin_amdgcn_readfirstlane(r);
        float br = bias[r];

        const _Float16* Wr = Wh + (size_t)r * (KDIM * KDIM);
        half4v aw1 = *(const half4v*)(Wr + lm * KDIM + kq);
        half4v aw2 = *(const half4v*)(Wr + lm * KDIM + 16 + kq);
        half4v aw3 = *(const half4v*)(Wr + (16 + lm) * KDIM + kq);
        half4v aw4 = *(const half4v*)(Wr + (16 + lm) * KDIM + 16 + kq);

        int slot = (g << 4) + lm;
        int ev  = e_l[slot];
        int snv = sn_l[slot];
        int dnv = dn_l[slot];
        bool valid = (ev >= 0);
        int sn = valid ? snv : 0;
        int dn = valid ? dnv : 0;

        const _Float16* Sp = Ah + (size_t)sn * KDIM;
        const _Float16* Dp = Ah + (size_t)dn * KDIM;
        half4v as1 = *(const half4v*)(Sp + kq);
        half4v as2 = *(const half4v*)(Sp + 16 + kq);
        half4v bd1 = *(const half4v*)(Dp + kq);
        half4v bd2 = *(const half4v*)(Dp + 16 + kq);

        f32x4 z1 = __builtin_amdgcn_mfma_f32_16x16x16f16(aw1, bd1, zeroF, 0, 0, 0);
        z1 = __builtin_amdgcn_mfma_f32_16x16x16f16(aw2, bd2, z1, 0, 0, 0);
        f32x4 z2 = __builtin_amdgcn_mfma_f32_16x16x16f16(aw3, bd1, zeroF, 0, 0, 0);
        z2 = __builtin_amdgcn_mfma_f32_16x16x16f16(aw4, bd2, z2, 0, 0, 0);

        half4v zb1, zb2;
        half2v t0 = __builtin_bit_cast(half2v, __builtin_amdgcn_cvt_pkrtz(z1[0], z1[1]));
        half2v t1 = __builtin_bit_cast(half2v, __builtin_amdgcn_cvt_pkrtz(z1[2], z1[3]));
        half2v t2 = __builtin_bit_cast(half2v, __builtin_amdgcn_cvt_pkrtz(z2[0], z2[1]));
        half2v t3 = __builtin_bit_cast(half2v, __builtin_amdgcn_cvt_pkrtz(z2[2], z2[3]));
        zb1[0] = t0[0]; zb1[1] = t0[1]; zb1[2] = t1[0]; zb1[3] = t1[1];
        zb2[0] = t2[0]; zb2[1] = t2[1]; zb2[2] = t3[0]; zb2[3] = t3[1];

        f32x4 c = __builtin_amdgcn_mfma_f32_16x16x16f16(as1, zb1, zeroF, 0, 0, 0);
        c = __builtin_amdgcn_mfma_f32_16x16x16f16(as2, zb2, c, 0, 0, 0);

        if (valid && diag_lane) out[ev] = c[lm & 3] + br;
    }
}
#endif

// ---- fallback (no MFMA / tiny ws / huge E): fp32, W staged in LDS ----
__global__ __launch_bounds__(256) void gather_unsorted_kernel(
    const float* __restrict__ A, const int* __restrict__ ei,
    const int* __restrict__ et,
    const float* __restrict__ logits, const float* __restrict__ la,
    const float* __restrict__ bias, float* __restrict__ out, int E, int R) {
    __shared__ float Wl[RMAX * 1032];
    int total_w = R * KDIM * KDIM;
    for (int t = threadIdx.x; t < total_w; t += blockDim.x) {
        int r = t / (KDIM * KDIM);
        int ij = t % (KDIM * KDIM);
        Wl[r * 1032 + ij] = gate_weight_(logits[t], la[t]);
    }
    __syncthreads();

    for (int e = blockIdx.x * blockDim.x + threadIdx.x; e < E;
         e += gridDim.x * blockDim.x) {
        int r = et[e];
        int sn = ei[e];
        int dn = ei[E + e];
        const float4* As = (const float4*)(A + (size_t)sn * KDIM);
        const float4* Ad = (const float4*)(A + (size_t)dn * KDIM);
        float sv[KDIM], dv[KDIM];
#pragma unroll
        for (int q = 0; q < KDIM / 4; q++) {
            float4 s4 = As[q];
            float4 d4 = Ad[q];
            sv[4 * q + 0] = s4.x; sv[4 * q + 1] = s4.y;
            sv[4 * q + 2] = s4.z; sv[4 * q + 3] = s4.w;
            dv[4 * q + 0] = d4.x; dv[4 * q + 1] = d4.y;
            dv[4 * q + 2] = d4.z; dv[4 * q + 3] = d4.w;
        }
        float totalv = 0.0f;
#pragma unroll
        for (int i = 0; i < KDIM; i++) {
            const float* Wrow = &Wl[r * 1032 + i * KDIM];
            float acc = 0.0f;
#pragma unroll
            for (int j = 0; j < KDIM / 4; j++) {
                float4 w4 = ((const float4*)Wrow)[j];
                acc = fmaf(w4.x, dv[4 * j + 0], acc);
                acc = fmaf(w4.y, dv[4 * j + 1], acc);
                acc = fmaf(w4.z, dv[4 * j + 2], acc);
                acc = fmaf(w4.w, dv[4 * j + 3], acc);
            }
            totalv = fmaf(sv[i], acc, totalv);
        }
        out[e] = totalv + bias[r];
    }
}

extern "C" void kernel_launch(void* const* d_in, const int* in_sizes, int n_in,
                              void* d_out, int out_size, void* d_ws, size_t ws_size,
                              hipStream_t stream) {
    const float* A      = (const float*)d_in[0];   // [N, 32]
    const int*   ei     = (const int*)d_in[1];     // [2, E]
    const int*   et     = (const int*)d_in[2];     // [E]
    const float* logits = (const float*)d_in[3];   // [R, 32, 32]
    const float* la     = (const float*)d_in[4];   // [R, 32, 32]
    const float* bias   = (const float*)d_in[5];   // [R]
    float* out = (float*)d_out;

    int E = in_sizes[2];
    int R = in_sizes[5];
    int n = in_sizes[3];   // R*K*K
    int nA = in_sizes[0];  // nodes * K

    // ws layout: Wh (16384) | Ah (nA*2)
    size_t need = 16384 + (size_t)nA * 2;

    // fused grid: ~512 edges per block, chunk must fit LDS (CAPL - 128 pad)
    int nblk = (E + 511) / 512;
    if (nblk > 2048) nblk = 2048;
    if (nblk < 1) nblk = 1;
    int chunk = (E + nblk - 1) / nblk;

#if USE_MFMA
    bool fast = (R <= RMAX) && ((nA & 3) == 0) && (ws_size >= need) &&
                (chunk <= CAPL - 128);
#else
    bool fast = false;
#endif

    if (fast) {
#if USE_MFMA
        char* ws = (char*)d_ws;
        _Float16* Wh = (_Float16*)(ws);
        _Float16* Ah = (_Float16*)(ws + 16384);

        prep3_kernel<<<512, 256, 0, stream>>>(logits, la, Wh, n, A, Ah, nA);
        fused_kernel<<<nblk, 256, 0, stream>>>(Ah, Wh, bias, ei, et, out, E, chunk);
#endif
    } else {
        int gblocks = (E + 255) / 256;
        if (gblocks > 2048) gblocks = 2048;
        gather_unsorted_kernel<<<gblocks, 256, 0, stream>>>(
            A, ei, et, logits, la, bias, out, E, R);
    }
}

// Round 14
// 95.959 us; speedup vs baseline: 1.3701x; 1.3701x over previous
//
#include <hip/hip_runtime.h>
#include <hip/hip_bf16.h>
#include <cstdint>

#define KDIM 32
#define RMAX 8
#define CAPL 1280   // LDS slots per block (chunk<=1152 + 128 pad)
#define GMAX 128

typedef _Float16 half2v __attribute__((ext_vector_type(2)));
typedef _Float16 half4v __attribute__((ext_vector_type(4)));
typedef float    f32x4  __attribute__((ext_vector_type(4)));

__device__ __forceinline__ float sigmoidf_(float x) {
    return 1.0f / (1.0f + expf(-x));
}

__device__ __forceinline__ float gate_weight_(float logit, float log_alpha) {
    // hard-concrete eval gate: pre = clip(la/temp, -2, 2); z = sig(pre)*1.2-0.1; clip[0,1]
    float pre = log_alpha * 1.5f;                 // / (2/3)
    pre = fminf(fmaxf(pre, -2.0f), 2.0f);
    float z = sigmoidf_(pre) * 1.2f - 0.1f;
    z = fminf(fmaxf(z, 0.0f), 1.0f);
    return sigmoidf_(logit) * z;
}

// ---- kernel 1: W->f16 + A->f16 conversion (validated prep pattern) ----
__global__ __launch_bounds__(256) void prep3_kernel(
    const float* __restrict__ logits, const float* __restrict__ la,
    _Float16* __restrict__ Wh, int n,
    const float* __restrict__ A, _Float16* __restrict__ Ah, int nA) {
    int g = blockIdx.x * blockDim.x + threadIdx.x;
    if (g < n) Wh[g] = (_Float16)gate_weight_(logits[g], la[g]);

    int nthreads = gridDim.x * blockDim.x;
    int n4 = nA >> 2;
    for (int i4 = g; i4 < n4; i4 += nthreads) {
        float4 v = ((const float4*)A)[i4];
        half2v h0; h0[0] = (_Float16)v.x; h0[1] = (_Float16)v.y;
        half2v h1; h1[0] = (_Float16)v.z; h1[1] = (_Float16)v.w;
        ((half2v*)Ah)[i4 * 2 + 0] = h0;
        ((half2v*)Ah)[i4 * 2 + 1] = h1;
    }
}

// ---- kernel 2: fused local-sort + MFMA compute.
// Block sorts its chunk into 8 LDS buckets padded to 16 (storing sn,dn,e),
// then each wave processes 16-edge groups with group-uniform relation.
// MFMA math identical to the round-9/12-validated gather4:
//   A-frag: lane l reg i = M[l%16][(l/16)*4+i]
//   B-frag: lane l reg i = M[(l/16)*4+i][l%16]
//   C:      lane l reg q = M[(l/16)*4+q][l%16]   (== B-frag mapping)
__global__ __launch_bounds__(256) void fused_kernel(
    const _Float16* __restrict__ Ah, const _Float16* __restrict__ Wh,
    const float* __restrict__ bias, const int* __restrict__ ei,
    const int* __restrict__ et, float* __restrict__ out, int E, int chunk) {
    __shared__ int sn_l[CAPL], dn_l[CAPL], e_l[CAPL];
    __shared__ int cnt[RMAX], cur[RMAX], pb[RMAX + 1];
    __shared__ int rg[GMAX];
    __shared__ int ng_s;

    int t = threadIdx.x;
    int b = blockIdx.x;
    int start = b * chunk;
    int end = start + chunk;
    if (end > E) end = E;

    // phase 0: zero counters
    if (t < RMAX) cnt[t] = 0;
    __syncthreads();

    // phase 1: count
    for (int i = start + t; i < end; i += 256) {
        atomicAdd(&cnt[et[i]], 1);
    }
    __syncthreads();

    // phase 2: padded prefix (pad each bucket to multiple of 16)
    if (t == 0) {
        int o = 0;
        pb[0] = 0;
#pragma unroll
        for (int r = 0; r < RMAX; r++) {
            cur[r] = o;
            o += (cnt[r] + 15) & ~15;
            pb[r + 1] = o;
        }
        ng_s = o >> 4;
    }
    __syncthreads();

    // phase 3a: group -> relation map
    int ng = ng_s;
    for (int g = t; g < ng; g += 256) {
        int s16 = g << 4;
        int r = 0;
#pragma unroll
        for (int rr = 1; rr < RMAX; rr++) r += (s16 >= pb[rr]) ? 1 : 0;
        rg[g] = r;
    }
    // phase 3b: pad slots (disjoint from placed slots)
#pragma unroll
    for (int r = 0; r < RMAX; r++) {
        int ps = pb[r] + cnt[r];
        int pe = pb[r + 1];
        for (int i = ps + t; i < pe; i += 256) {
            e_l[i] = -1; sn_l[i] = 0; dn_l[i] = 0;
        }
    }
    // phase 3c: place (coalesced global reads, LDS-atomic positions)
    for (int i = start + t; i < end; i += 256) {
        int r = et[i];
        int sn = ei[i];
        int dn = ei[E + i];
        int pos = atomicAdd(&cur[r], 1);
        sn_l[pos] = sn; dn_l[pos] = dn; e_l[pos] = i;
    }
    __syncthreads();

    // phase 4: compute, one 16-edge group per wave-iteration
    int wid = t >> 6;
    int lane = t & 63;
    int lm = lane & 15;
    int lg = lane >> 4;
    int kq = lg * 4;
    f32x4 zeroF = {0.0f, 0.0f, 0.0f, 0.0f};
    bool diag_lane = (lg == (lm >> 2));

    for (int g = wid; g < ng; g += 4) {
        int r = rg[g];                       // LDS broadcast, group-uniform
        r = __builtin_amdgcn_readfirstlane(r);
        float br = bias[r];

        const _Float16* Wr = Wh + (size_t)r * (KDIM * KDIM);
        half4v aw1 = *(const half4v*)(Wr + lm * KDIM + kq);
        half4v aw2 = *(const half4v*)(Wr + lm * KDIM + 16 + kq);
        half4v aw3 = *(const half4v*)(Wr + (16 + lm) * KDIM + kq);
        half4v aw4 = *(const half4v*)(Wr + (16 + lm) * KDIM + 16 + kq);

        int slot = (g << 4) + lm;
        int ev  = e_l[slot];
        int snv = sn_l[slot];
        int dnv = dn_l[slot];
        bool valid = (ev >= 0);
        int sn = valid ? snv : 0;
        int dn = valid ? dnv : 0;

        const _Float16* Sp = Ah + (size_t)sn * KDIM;
        const _Float16* Dp = Ah + (size_t)dn * KDIM;
        half4v as1 = *(const half4v*)(Sp + kq);
        half4v as2 = *(const half4v*)(Sp + 16 + kq);
        half4v bd1 = *(const half4v*)(Dp + kq);
        half4v bd2 = *(const half4v*)(Dp + 16 + kq);

        f32x4 z1 = __builtin_amdgcn_mfma_f32_16x16x16f16(aw1, bd1, zeroF, 0, 0, 0);
        z1 = __builtin_amdgcn_mfma_f32_16x16x16f16(aw2, bd2, z1, 0, 0, 0);
        f32x4 z2 = __builtin_amdgcn_mfma_f32_16x16x16f16(aw3, bd1, zeroF, 0, 0, 0);
        z2 = __builtin_amdgcn_mfma_f32_16x16x16f16(aw4, bd2, z2, 0, 0, 0);

        half4v zb1, zb2;
        half2v t0 = __builtin_bit_cast(half2v, __builtin_amdgcn_cvt_pkrtz(z1[0], z1[1]));
        half2v t1 = __builtin_bit_cast(half2v, __builtin_amdgcn_cvt_pkrtz(z1[2], z1[3]));
        half2v t2 = __builtin_bit_cast(half2v, __builtin_amdgcn_cvt_pkrtz(z2[0], z2[1]));
        half2v t3 = __builtin_bit_cast(half2v, __builtin_amdgcn_cvt_pkrtz(z2[2], z2[3]));
        zb1[0] = t0[0]; zb1[1] = t0[1]; zb1[2] = t1[0]; zb1[3] = t1[1];
        zb2[0] = t2[0]; zb2[1] = t2[1]; zb2[2] = t3[0]; zb2[3] = t3[1];

        f32x4 c = __builtin_amdgcn_mfma_f32_16x16x16f16(as1, zb1, zeroF, 0, 0, 0);
        c = __builtin_amdgcn_mfma_f32_16x16x16f16(as2, zb2, c, 0, 0, 0);

        if (valid && diag_lane) out[ev] = c[lm & 3] + br;
    }
}

// ---- fallback (tiny ws / huge E / odd R): fp32, W staged in LDS ----
__global__ __launch_bounds__(256) void gather_unsorted_kernel(
    const float* __restrict__ A, const int* __restrict__ ei,
    const int* __restrict__ et,
    const float* __restrict__ logits, const float* __restrict__ la,
    const float* __restrict__ bias, float* __restrict__ out, int E, int R) {
    __shared__ float Wl[RMAX * 1032];
    int total_w = R * KDIM * KDIM;
    for (int t = threadIdx.x; t < total_w; t += blockDim.x) {
        int r = t / (KDIM * KDIM);
        int ij = t % (KDIM * KDIM);
        Wl[r * 1032 + ij] = gate_weight_(logits[t], la[t]);
    }
    __syncthreads();

    for (int e = blockIdx.x * blockDim.x + threadIdx.x; e < E;
         e += gridDim.x * blockDim.x) {
        int r = et[e];
        int sn = ei[e];
        int dn = ei[E + e];
        const float4* As = (const float4*)(A + (size_t)sn * KDIM);
        const float4* Ad = (const float4*)(A + (size_t)dn * KDIM);
        float sv[KDIM], dv[KDIM];
#pragma unroll
        for (int q = 0; q < KDIM / 4; q++) {
            float4 s4 = As[q];
            float4 d4 = Ad[q];
            sv[4 * q + 0] = s4.x; sv[4 * q + 1] = s4.y;
            sv[4 * q + 2] = s4.z; sv[4 * q + 3] = s4.w;
            dv[4 * q + 0] = d4.x; dv[4 * q + 1] = d4.y;
            dv[4 * q + 2] = d4.z; dv[4 * q + 3] = d4.w;
        }
        float totalv = 0.0f;
#pragma unroll
        for (int i = 0; i < KDIM; i++) {
            const float* Wrow = &Wl[r * 1032 + i * KDIM];
            float acc = 0.0f;
#pragma unroll
            for (int j = 0; j < KDIM / 4; j++) {
                float4 w4 = ((const float4*)Wrow)[j];
                acc = fmaf(w4.x, dv[4 * j + 0], acc);
                acc = fmaf(w4.y, dv[4 * j + 1], acc);
                acc = fmaf(w4.z, dv[4 * j + 2], acc);
                acc = fmaf(w4.w, dv[4 * j + 3], acc);
            }
            totalv = fmaf(sv[i], acc, totalv);
        }
        out[e] = totalv + bias[r];
    }
}

extern "C" void kernel_launch(void* const* d_in, const int* in_sizes, int n_in,
                              void* d_out, int out_size, void* d_ws, size_t ws_size,
                              hipStream_t stream) {
    const float* A      = (const float*)d_in[0];   // [N, 32]
    const int*   ei     = (const int*)d_in[1];     // [2, E]
    const int*   et     = (const int*)d_in[2];     // [E]
    const float* logits = (const float*)d_in[3];   // [R, 32, 32]
    const float* la     = (const float*)d_in[4];   // [R, 32, 32]
    const float* bias   = (const float*)d_in[5];   // [R]
    float* out = (float*)d_out;

    int E = in_sizes[2];
    int R = in_sizes[5];
    int n = in_sizes[3];   // R*K*K
    int nA = in_sizes[0];  // nodes * K

    // ws layout: Wh (16384) | Ah (nA*2)
    size_t need = 16384 + (size_t)nA * 2;

    // fused grid: ~512 edges per block, chunk must fit LDS (CAPL - 128 pad)
    int nblk = (E + 511) / 512;
    if (nblk > 2048) nblk = 2048;
    if (nblk < 1) nblk = 1;
    int chunk = (E + nblk - 1) / nblk;

    // size-based selection ONLY (host must not depend on device __has_builtin)
    bool fast = (R <= RMAX) && ((nA & 3) == 0) && (ws_size >= need) &&
                (chunk <= CAPL - 128);

    if (fast) {
        char* ws = (char*)d_ws;
        _Float16* Wh = (_Float16*)(ws);
        _Float16* Ah = (_Float16*)(ws + 16384);

        prep3_kernel<<<512, 256, 0, stream>>>(logits, la, Wh, n, A, Ah, nA);
        fused_kernel<<<nblk, 256, 0, stream>>>(Ah, Wh, bias, ei, et, out, E, chunk);
    } else {
        int gblocks = (E + 255) / 256;
        if (gblocks > 2048) gblocks = 2048;
        gather_unsorted_kernel<<<gblocks, 256, 0, stream>>>(
            A, ei, et, logits, la, bias, out, E, R);
    }
}